// Round 2
// baseline (133.469 us; speedup 1.0000x reference)
//
#include <hip/hip_runtime.h>
#include <math.h>

// Second-order IIR (B=1024 rows, T=16384), fp32.
// One row per block (1024 blocks x 256 threads = 4 blocks/CU, one residency wave).
// Row processed in two 8192-element halves. Per half:
//   pass1: each thread loads its 32-element chunk DIRECTLY from global
//          (8x dwordx4, per-lane contiguous 128B -> every HBM line fetched once),
//          computes the 3-tap FIR v[] into VGPRs and the zero-state chunk response.
//   scan : wave-0 Kogge-Stone affine scan over the 256 chunk states (LDS = 2KB only).
//   pass2: exact recurrence from the scanned incoming state, y stored DIRECTLY
//          to global (8x dwordx4 per lane).
// No LDS data staging, 2 barriers per half (vs 5 before).

#define TLEN  16384
#define HALF  8192
#define NT    256
#define CK    32
#define NCH   256
#define CARRY (2*NCH)

__device__ __forceinline__ void mat2_sq(float& m00, float& m01, float& m10, float& m11) {
    float t00 = m00*m00 + m01*m10;
    float t01 = m00*m01 + m01*m11;
    float t10 = m10*m00 + m11*m10;
    float t11 = m10*m01 + m11*m11;
    m00 = t00; m01 = t01; m10 = t10; m11 = t11;
}

__global__ __launch_bounds__(NT, 4)
void iir_kernel(const float* __restrict__ bc,
                const float* __restrict__ rho_p,
                const float* __restrict__ psi_p,
                const float* __restrict__ u_in,
                const float* __restrict__ y_init,
                const float* __restrict__ u_init,
                float* __restrict__ y_out)
{
    __shared__ float sc[2*NCH + 2];   // chunk states + inter-half carry (2056 B)
    const int row = blockIdx.x;
    const int tid = threadIdx.x;

    const float rho = rho_p[0];
    const float psi = psi_p[0];
    const float r   = 1.0f / (1.0f + expf(-rho));
    const float th  = 3.14159265358979323846f / (1.0f + expf(-psi)); // pi*sigmoid(psi)
    const float a1  = -2.0f * r * cosf(th);
    const float a2  = r * r;
    const float b0  = bc[0], b1 = bc[1], b2 = bc[2];

    const float* urow = u_in  + (size_t)row * TLEN;
    float*       orow = y_out + (size_t)row * TLEN;

    for (int h = 0; h < 2; ++h) {
        const float* uc0 = urow + h * HALF + CK * tid;   // this thread's chunk

        // ---- boundary u's (u[-1], u[-2] of the chunk) ----
        float um2, um1;
        if (tid == 0 && h == 0) {
            um2 = u_init[2*row + 1];     // u_ext[0] = u_init[:,1]
            um1 = u_init[2*row + 0];     // u_ext[1] = u_init[:,0]
        } else {
            float2 ub = *(const float2*)(uc0 - 2);       // 8B-aligned
            um2 = ub.x; um1 = ub.y;
        }

        // ---- pass 1: direct global load + FIR + zero-state chunk response ----
        float uu[CK];
        #pragma unroll
        for (int k = 0; k < CK/4; ++k)
            *(float4*)&uu[4*k] = ((const float4*)uc0)[k];

        float v[CK];
        float y1 = 0.0f, y2 = 0.0f;
        #pragma unroll
        for (int j = 0; j < CK; ++j) {
            float uc = uu[j];
            float vv = fmaf(b2, um2, fmaf(b1, um1, b0 * uc));
            v[j] = vv;
            float y = fmaf(-a1, y1, fmaf(-a2, y2, vv));
            y2 = y1; y1 = y;
            um2 = um1; um1 = uc;
        }
        sc[2*tid]     = y1;              // chunk d = (y[last], y[last-1])
        sc[2*tid + 1] = y2;
        __syncthreads();

        // ---- wave-0 affine scan over 256 chunk states ----
        if (tid < 64) {
            const int l = tid;
            // M = A^CK = A^32 via 5 squarings; A = [[-a1,-a2],[1,0]]
            float m00 = -a1, m01 = -a2, m10 = 1.0f, m11 = 0.0f;
            #pragma unroll
            for (int s = 0; s < 5; ++s) mat2_sq(m00, m01, m10, m11);

            float da[4], db[4];
            #pragma unroll
            for (int m = 0; m < 4; ++m) {
                da[m] = sc[8*l + 2*m];
                db[m] = sc[8*l + 2*m + 1];
            }

            float seed0 = 0.0f, seed1 = 0.0f;
            if (l == 0) {
                if (h == 0) { seed0 = y_init[2*row]; seed1 = y_init[2*row + 1]; }
                else        { seed0 = sc[CARRY]; seed1 = sc[CARRY + 1]; }
            }
            // serial fold of this lane's 4 chunks (lane 0 seeded with s_{-1})
            float s0 = seed0, s1 = seed1;
            #pragma unroll
            for (int m = 0; m < 4; ++m) {
                float n0 = fmaf(m00, s0, fmaf(m01, s1, da[m]));
                float n1 = fmaf(m10, s0, fmaf(m11, s1, db[m]));
                s0 = n0; s1 = n1;
            }
            // W = M^4; Kogge-Stone inclusive scan over 64 lanes
            float w00 = m00, w01 = m01, w10 = m10, w11 = m11;
            mat2_sq(w00, w01, w10, w11);
            mat2_sq(w00, w01, w10, w11);
            #pragma unroll
            for (int p = 0; p < 6; ++p) {
                float o0 = __shfl_up(s0, 1 << p);
                float o1 = __shfl_up(s1, 1 << p);
                if (l >= (1 << p)) {
                    s0 = fmaf(w00, o0, fmaf(w01, o1, s0));
                    s1 = fmaf(w10, o0, fmaf(w11, o1, s1));
                }
                if (p < 5) mat2_sq(w00, w01, w10, w11);
            }
            // incoming state for chunk 4l = prefix of lane l-1 (or seed for l=0)
            float p0 = __shfl_up(s0, 1);
            float p1 = __shfl_up(s1, 1);
            if (l == 0) { p0 = seed0; p1 = seed1; }
            float c0 = p0, c1 = p1;
            #pragma unroll
            for (int m = 0; m < 4; ++m) {
                sc[2*(4*l + m)]     = c0;
                sc[2*(4*l + m) + 1] = c1;
                float n0 = fmaf(m00, c0, fmaf(m01, c1, da[m]));
                float n1 = fmaf(m10, c0, fmaf(m11, c1, db[m]));
                c0 = n0; c1 = n1;
            }
        }
        __syncthreads();

        // ---- pass 2: exact recurrence from incoming state, store direct ----
        float y1f = sc[2*tid];           // y[chunk_start-1]
        float y2f = sc[2*tid + 1];       // y[chunk_start-2]
        float* oc0 = orow + h * HALF + CK * tid;
        float yy[CK];
        #pragma unroll
        for (int j = 0; j < CK; ++j) {
            float y = fmaf(-a1, y1f, fmaf(-a2, y2f, v[j]));
            yy[j] = y;
            y2f = y1f; y1f = y;
        }
        #pragma unroll
        for (int k = 0; k < CK/4; ++k)
            ((float4*)oc0)[k] = *(const float4*)&yy[4*k];

        if (tid == NT - 1) {             // exact carry into next half
            sc[CARRY]     = y1f;
            sc[CARRY + 1] = y2f;
        }
        // no barrier needed here: each thread only re-writes its own sc slot in
        // the next half's pass 1, and the pre-scan barrier orders the carry.
    }
}

extern "C" void kernel_launch(void* const* d_in, const int* in_sizes, int n_in,
                              void* d_out, int out_size, void* d_ws, size_t ws_size,
                              hipStream_t stream) {
    const float* bc    = (const float*)d_in[0];
    const float* rho   = (const float*)d_in[1];
    const float* psi   = (const float*)d_in[2];
    const float* u_in  = (const float*)d_in[3];
    const float* y_in  = (const float*)d_in[4];
    const float* u_ini = (const float*)d_in[5];
    float* y = (float*)d_out;
    const int B = in_sizes[3] / TLEN;    // 1024
    iir_kernel<<<B, NT, 0, stream>>>(bc, rho, psi, u_in, y_in, u_ini, y);
}